// Round 6
// baseline (2950.544 us; speedup 1.0000x reference)
//
#include <hip/hip_runtime.h>
#include <hip/hip_bf16.h>
#include <math.h>

#define T_STEPS 512
#define BATCH   1024
#define NB      16
#define NTILE   (BATCH / NB)   // 64 batch-tiles

typedef __attribute__((ext_vector_type(8))) short short8;
typedef __attribute__((ext_vector_type(4))) float f32x4;

#define MFMA16(A, B, C) __builtin_amdgcn_mfma_f32_16x16x32_bf16((A), (B), (C), 0, 0, 0)

__device__ __forceinline__ float fast_sigm(float z) {
    return __fdividef(1.0f, 1.0f + __expf(-z));
}
__device__ __forceinline__ float fast_tanh(float z) {
    return fmaf(2.0f, __fdividef(1.0f, 1.0f + __expf(-2.0f * z)), -1.0f);
}
__device__ __forceinline__ unsigned short f2bf(float f) {
    unsigned int u = __float_as_uint(f);
    u += 0x7fffu + ((u >> 16) & 1u);
    return (unsigned short)(u >> 16);
}

// linear k-slot gather: element e <- p[e]
__device__ __forceinline__ short8 ldfrag_lin(const float* __restrict__ p) {
    short8 r;
#pragma unroll
    for (int e = 0; e < 8; ++e) r[e] = (short)f2bf(p[e]);
    return r;
}
// sigma2 k-slot gather within a 32-col block: col = (e>>2)*16 + lg*4 + (e&3)
// (matches the lane-natural packing of MFMA C-results -> h B-fragments)
__device__ __forceinline__ short8 ldfrag_s2(const float* __restrict__ p, int lg) {
    short8 r;
#pragma unroll
    for (int e = 0; e < 8; ++e) r[e] = (short)f2bf(p[(e >> 2) * 16 + lg * 4 + (e & 3)]);
    return r;
}

// ===========================================================================
// K_A: layer-1 REVERSE. 64 blocks x 64 threads (1 wave = 16 batches, whole
// recurrence). z^T[256,16] = Whh(A, static VGPR frags) x h(B, registers).
// 48 MFMA/step (16 M-tiles x {h0-31, h32-63, [x,1]-tile}). NO LDS h, NO
// barriers, NO shuffles in the loop. h_r archived bf16 to ws.
// ===========================================================================
__global__ __launch_bounds__(64, 1) void l1rev_kernel(
    const float* __restrict__ x,
    const float* __restrict__ whh1r, const float* __restrict__ wih1r,
    const float* __restrict__ b1r,
    unsigned short* __restrict__ arch)     // [NTILE][T][NB][64]
{
    __shared__ float xT[T_STEPS][17];
    const int bt = blockIdx.x, l = threadIdx.x;
    const int lg = l >> 4, lr = l & 15;

    for (int i = l; i < T_STEPS * NB; i += 64) {
        const int b = i >> 9, t = i & 511;
        xT[t][b] = x[(size_t)(bt * NB + b) * T_STEPS + t];
    }

    short8 WA[16][2], XA[16];
#pragma unroll
    for (int m = 0; m < 16; ++m) {
        const int row = m * 16 + lr;                  // gate-row (i,f,g,o blocks of 64)
        WA[m][0] = ldfrag_s2(whh1r + row * 64, lg);
        WA[m][1] = ldfrag_s2(whh1r + row * 64 + 32, lg);
        short8 xf = {0, 0, 0, 0, 0, 0, 0, 0};
        if (lg == 0) { xf[0] = (short)f2bf(wih1r[row]); xf[1] = (short)f2bf(b1r[row]); }
        XA[m] = xf;
    }

    float cst[16];
#pragma unroll
    for (int i = 0; i < 16; ++i) cst[i] = 0.f;
    short8 hb0 = {0, 0, 0, 0, 0, 0, 0, 0};
    short8 hb1 = {0, 0, 0, 0, 0, 0, 0, 0};
    unsigned short* __restrict__ ab = arch + (size_t)bt * T_STEPS * NB * 64;

    __syncthreads();
    float xcur = xT[T_STEPS - 1][lr];

    for (int t = T_STEPS - 1; t >= 0; --t) {
        const float xnext = (t > 0) ? xT[t - 1][lr] : 0.f;
        short8 bx = {0, 0, 0, 0, 0, 0, 0, 0};
        if (lg == 0) { bx[0] = (short)f2bf(xcur); bx[1] = (short)0x3F80; }  // [x, 1]
        f32x4 z[16];
#pragma unroll
        for (int m = 0; m < 16; ++m) {
            f32x4 a = {0.f, 0.f, 0.f, 0.f};
            a = MFMA16(WA[m][0], hb0, a);
            a = MFMA16(WA[m][1], hb1, a);
            a = MFMA16(XA[m], bx, a);
            z[m] = a;
        }
        unsigned short hb[4][4];
#pragma unroll
        for (int uh = 0; uh < 4; ++uh) {
#pragma unroll
            for (int j = 0; j < 4; ++j) {
                const float vi = fast_sigm(z[uh][j]);
                const float vf = fast_sigm(z[4 + uh][j]);
                const float vg = fast_tanh(z[8 + uh][j]);
                const float vo = fast_sigm(z[12 + uh][j]);
                float& cc = cst[uh * 4 + j];
                cc = fmaf(vf, cc, vi * vg);
                hb[uh][j] = f2bf(vo * fast_tanh(cc));
            }
        }
#pragma unroll
        for (int e = 0; e < 8; ++e) {
            hb0[e] = (short)hb[e >> 2][e & 3];        // units  0..31 (sigma2 order)
            hb1[e] = (short)hb[2 + (e >> 2)][e & 3];  // units 32..63
        }
#pragma unroll
        for (int uh = 0; uh < 4; ++uh) {
            uint2 v;
            v.x = (unsigned)hb[uh][0] | ((unsigned)hb[uh][1] << 16);
            v.y = (unsigned)hb[uh][2] | ((unsigned)hb[uh][3] << 16);
            *(uint2*)(ab + ((size_t)t * NB + lr) * 64 + uh * 16 + lg * 4) = v;
        }
        xcur = xnext;
    }
}

// ===========================================================================
// K_B: 64 blocks x 128 threads. wave0: layer-1 FORWARD (same register scheme,
// publishes h via 4 ds_write_b64 into padded LDS). wave1: layer-2 forward,
// skewed 1 step: 48 MFMA/step (hf from LDS, hr prefetched from archive,
// h2 + bias in-register). ONE 2-wave barrier per step. Epilogue (wave1):
// layer-2 reverse single step @ T-1 (zero state) + MLP head, all via MFMA.
// ===========================================================================
__global__ __launch_bounds__(128, 1) void l1fwd_l2_kernel(
    const float* __restrict__ x,
    const float* __restrict__ wih1f, const float* __restrict__ whh1f, const float* __restrict__ b1f,
    const float* __restrict__ wih2f, const float* __restrict__ whh2f, const float* __restrict__ b2f,
    const float* __restrict__ wih2r, const float* __restrict__ b2r,
    const float* __restrict__ w_fc1, const float* __restrict__ b_fc1,
    const float* __restrict__ w_out, const float* __restrict__ b_out,
    const unsigned short* __restrict__ arch,
    float* __restrict__ out)
{
    __shared__ float xT[T_STEPS][17];
    __shared__ short hfX[2][16][72];    // padded 72: conflict-free b128 reads

    const int bt = blockIdx.x, tid = threadIdx.x;
    const int wv = tid >> 6, l = tid & 63;
    const int lg = l >> 4, lr = l & 15;
    const unsigned short* __restrict__ ab = arch + (size_t)bt * T_STEPS * NB * 64;

    for (int i = tid; i < T_STEPS * NB; i += 128) {
        const int b = i >> 9, t = i & 511;
        xT[t][b] = x[(size_t)(bt * NB + b) * T_STEPS + t];
    }

    // Shared register pool (per-wave contents differ; same storage -> no
    // union-liveness VGPR blowup across the wv branch).
    short8 AF[48];
    f32x4 z[16];
    float cst[16];
    short8 Bh0 = {0, 0, 0, 0, 0, 0, 0, 0};   // w0: h frag lo | w1: hr prefetch lo
    short8 Bh1 = {0, 0, 0, 0, 0, 0, 0, 0};   // w0: h frag hi | w1: hr prefetch hi
    short8 Bx  = {0, 0, 0, 0, 0, 0, 0, 0};   // w0: scratch   | w1: h2 frag
    short8 Bb  = {0, 0, 0, 0, 0, 0, 0, 0};   // w1: [1,0..] bias B-frag

    if (wv == 0) {
#pragma unroll
        for (int m = 0; m < 16; ++m) {
            const int row = m * 16 + lr;
            AF[m]      = ldfrag_s2(whh1f + row * 64, lg);
            AF[16 + m] = ldfrag_s2(whh1f + row * 64 + 32, lg);
            short8 xf = {0, 0, 0, 0, 0, 0, 0, 0};
            if (lg == 0) { xf[0] = (short)f2bf(wih1f[row]); xf[1] = (short)f2bf(b1f[row]); }
            AF[32 + m] = xf;
        }
    } else {
#pragma unroll
        for (int m = 0; m < 8; ++m) {
            const int row = m * 16 + lr;                 // L2 gate-row
            AF[m * 6 + 0] = ldfrag_lin(wih2f + row * 128 + lg * 8);        // hf k 0-31
            AF[m * 6 + 1] = ldfrag_lin(wih2f + row * 128 + 32 + lg * 8);   // hf k 32-63
            AF[m * 6 + 2] = ldfrag_lin(wih2f + row * 128 + 64 + lg * 8);   // hr k 0-31
            AF[m * 6 + 3] = ldfrag_lin(wih2f + row * 128 + 96 + lg * 8);   // hr k 32-63
            AF[m * 6 + 4] = ldfrag_s2(whh2f + row * 32, lg);               // h2
            short8 bf = {0, 0, 0, 0, 0, 0, 0, 0};
            if (lg == 0) bf[0] = (short)f2bf(b2f[row]);
            AF[m * 6 + 5] = bf;                                            // bias A
        }
        if (lg == 0) Bb[0] = (short)0x3F80;              // B = [1, 0, ...]
        Bh0 = *(const short8*)(ab + (size_t)lr * 64 + lg * 8);        // hr(0)
        Bh1 = *(const short8*)(ab + (size_t)lr * 64 + 32 + lg * 8);
    }
#pragma unroll
    for (int i = 0; i < 16; ++i) cst[i] = 0.f;

    __syncthreads();
    float xcur = (wv == 0) ? xT[0][lr] : 0.f;

    for (int i = 0; i <= T_STEPS; ++i) {
        if (wv == 0) {
            if (i < T_STEPS) {
                const float xnext = (i + 1 < T_STEPS) ? xT[i + 1][lr] : 0.f;
                short8 bx = {0, 0, 0, 0, 0, 0, 0, 0};
                if (lg == 0) { bx[0] = (short)f2bf(xcur); bx[1] = (short)0x3F80; }
#pragma unroll
                for (int m = 0; m < 16; ++m) {
                    f32x4 a = {0.f, 0.f, 0.f, 0.f};
                    a = MFMA16(AF[m], Bh0, a);
                    a = MFMA16(AF[16 + m], Bh1, a);
                    a = MFMA16(AF[32 + m], bx, a);
                    z[m] = a;
                }
                unsigned short hb[4][4];
#pragma unroll
                for (int uh = 0; uh < 4; ++uh) {
#pragma unroll
                    for (int j = 0; j < 4; ++j) {
                        const float vi = fast_sigm(z[uh][j]);
                        const float vf = fast_sigm(z[4 + uh][j]);
                        const float vg = fast_tanh(z[8 + uh][j]);
                        const float vo = fast_sigm(z[12 + uh][j]);
                        float& cc = cst[uh * 4 + j];
                        cc = fmaf(vf, cc, vi * vg);
                        hb[uh][j] = f2bf(vo * fast_tanh(cc));
                    }
                }
#pragma unroll
                for (int e = 0; e < 8; ++e) {
                    Bh0[e] = (short)hb[e >> 2][e & 3];
                    Bh1[e] = (short)hb[2 + (e >> 2)][e & 3];
                }
#pragma unroll
                for (int uh = 0; uh < 4; ++uh) {
                    uint2 v;
                    v.x = (unsigned)hb[uh][0] | ((unsigned)hb[uh][1] << 16);
                    v.y = (unsigned)hb[uh][2] | ((unsigned)hb[uh][3] << 16);
                    *(uint2*)&hfX[i & 1][lr][uh * 16 + lg * 4] = v;
                }
                xcur = xnext;
            }
        } else {
            if (i >= 1) {
                const int s = i - 1;
                const short8 f0 = *(const short8*)&hfX[s & 1][lr][lg * 8];
                const short8 f1 = *(const short8*)&hfX[s & 1][lr][32 + lg * 8];
                const short8 r0 = Bh0, r1 = Bh1;
                if (i < T_STEPS) {   // prefetch hr(i) for next iteration
                    Bh0 = *(const short8*)(ab + ((size_t)i * NB + lr) * 64 + lg * 8);
                    Bh1 = *(const short8*)(ab + ((size_t)i * NB + lr) * 64 + 32 + lg * 8);
                }
#pragma unroll
                for (int m = 0; m < 8; ++m) {
                    f32x4 a = {0.f, 0.f, 0.f, 0.f}, b = {0.f, 0.f, 0.f, 0.f};
                    a = MFMA16(AF[m * 6 + 0], f0, a);
                    a = MFMA16(AF[m * 6 + 2], r0, a);
                    a = MFMA16(AF[m * 6 + 4], Bx, a);
                    b = MFMA16(AF[m * 6 + 1], f1, b);
                    b = MFMA16(AF[m * 6 + 3], r1, b);
                    b = MFMA16(AF[m * 6 + 5], Bb, b);
                    z[m] = a + b;
                }
                unsigned short h2b[2][4];
#pragma unroll
                for (int uh = 0; uh < 2; ++uh) {
#pragma unroll
                    for (int j = 0; j < 4; ++j) {
                        const float vi = fast_sigm(z[uh][j]);
                        const float vf = fast_sigm(z[2 + uh][j]);
                        const float vg = fast_tanh(z[4 + uh][j]);
                        const float vo = fast_sigm(z[6 + uh][j]);
                        float& cc = cst[uh * 4 + j];
                        cc = fmaf(vf, cc, vi * vg);
                        h2b[uh][j] = f2bf(vo * fast_tanh(cc));
                    }
                }
#pragma unroll
                for (int e = 0; e < 8; ++e) Bx[e] = (short)h2b[e >> 2][e & 3];
            }
        }
        __syncthreads();
    }

    // ===== wave1 epilogue: layer-2 reverse single step @ T-1 + MLP head ====
    if (wv == 1) {
#pragma unroll
        for (int m = 0; m < 8; ++m) {
            const int row = m * 16 + lr;
            AF[m * 5 + 0] = ldfrag_lin(wih2r + row * 128 + lg * 8);
            AF[m * 5 + 1] = ldfrag_lin(wih2r + row * 128 + 32 + lg * 8);
            AF[m * 5 + 2] = ldfrag_lin(wih2r + row * 128 + 64 + lg * 8);
            AF[m * 5 + 3] = ldfrag_lin(wih2r + row * 128 + 96 + lg * 8);
            short8 bf = {0, 0, 0, 0, 0, 0, 0, 0};
            if (lg == 0) bf[0] = (short)f2bf(b2r[row]);
            AF[m * 5 + 4] = bf;
        }
        const short8 f0 = *(const short8*)&hfX[(T_STEPS - 1) & 1][lr][lg * 8];
        const short8 f1 = *(const short8*)&hfX[(T_STEPS - 1) & 1][lr][32 + lg * 8];
        const short8 r0 = *(const short8*)(ab + ((size_t)(T_STEPS - 1) * NB + lr) * 64 + lg * 8);
        const short8 r1 = *(const short8*)(ab + ((size_t)(T_STEPS - 1) * NB + lr) * 64 + 32 + lg * 8);
#pragma unroll
        for (int m = 0; m < 8; ++m) {
            f32x4 a = {0.f, 0.f, 0.f, 0.f}, b = {0.f, 0.f, 0.f, 0.f};
            a = MFMA16(AF[m * 5 + 0], f0, a);
            a = MFMA16(AF[m * 5 + 2], r0, a);
            a = MFMA16(AF[m * 5 + 4], Bb, a);
            b = MFMA16(AF[m * 5 + 1], f1, b);
            b = MFMA16(AF[m * 5 + 3], r1, b);
            z[m] = a + b;
        }
        short8 BR = {0, 0, 0, 0, 0, 0, 0, 0};   // h2r B-frag (sigma2 order)
#pragma unroll
        for (int uh = 0; uh < 2; ++uh) {
#pragma unroll
            for (int j = 0; j < 4; ++j) {
                const float vi = fast_sigm(z[uh][j]);            // f-gate irrelevant: c0=0
                const float vg = fast_tanh(z[4 + uh][j]);
                const float vo = fast_sigm(z[6 + uh][j]);
                BR[uh * 4 + j] = (short)f2bf(vo * fast_tanh(vi * vg));
            }
        }
        // head: z64 = relu(W_fc1.[h2f; h2r] + b_fc1); out = sigm(z64 . w_out + b_out)
#pragma unroll
        for (int m = 0; m < 4; ++m) {
            const int row = m * 16 + lr;
            AF[m * 3 + 0] = ldfrag_s2(w_fc1 + row * 64, lg);
            AF[m * 3 + 1] = ldfrag_s2(w_fc1 + row * 64 + 32, lg);
            short8 bf = {0, 0, 0, 0, 0, 0, 0, 0};
            if (lg == 0) bf[0] = (short)f2bf(b_fc1[row]);
            AF[m * 3 + 2] = bf;
        }
        float part = 0.f;
#pragma unroll
        for (int m = 0; m < 4; ++m) {
            f32x4 a = {0.f, 0.f, 0.f, 0.f};
            a = MFMA16(AF[m * 3 + 0], Bx, a);    // Bx = h2f(T-1) frag from loop
            a = MFMA16(AF[m * 3 + 1], BR, a);
            a = MFMA16(AF[m * 3 + 2], Bb, a);
#pragma unroll
            for (int j = 0; j < 4; ++j) {
                const int row = m * 16 + lg * 4 + j;
                part += fmaxf(a[j], 0.f) * w_out[row];
            }
        }
        part += __shfl_xor(part, 16, 64);
        part += __shfl_xor(part, 32, 64);
        if (l < 16) out[bt * NB + lr] = fast_sigm(part + b_out[0]);
    }
}

// ---------------------------------------------------------------------------
extern "C" void kernel_launch(void* const* d_in, const int* in_sizes, int n_in,
                              void* d_out, int out_size, void* d_ws, size_t ws_size,
                              hipStream_t stream) {
    const float* x     = (const float*)d_in[0];
    const float* wih1f = (const float*)d_in[1];
    const float* whh1f = (const float*)d_in[2];
    const float* b1f   = (const float*)d_in[3];
    const float* wih1r = (const float*)d_in[4];
    const float* whh1r = (const float*)d_in[5];
    const float* b1r   = (const float*)d_in[6];
    const float* wih2f = (const float*)d_in[7];
    const float* whh2f = (const float*)d_in[8];
    const float* b2f   = (const float*)d_in[9];
    const float* wih2r = (const float*)d_in[10];
    // d_in[11] = whh2r unused: layer-2 reverse runs exactly one step from zero state
    const float* b2r   = (const float*)d_in[12];
    const float* w_fc1 = (const float*)d_in[13];
    const float* b_fc1 = (const float*)d_in[14];
    const float* w_out = (const float*)d_in[15];
    const float* b_out = (const float*)d_in[16];
    float* out = (float*)d_out;

    // 64 MB hr archive — ws proven >= 64 MB by rounds 4/5 (MFMA path executed).
    unsigned short* arch = (unsigned short*)d_ws;

    l1rev_kernel<<<dim3(NTILE), dim3(64), 0, stream>>>(x, whh1r, wih1r, b1r, arch);
    l1fwd_l2_kernel<<<dim3(NTILE), dim3(128), 0, stream>>>(
        x, wih1f, whh1f, b1f, wih2f, whh2f, b2f, wih2r, b2r,
        w_fc1, b_fc1, w_out, b_out, arch, out);
}

// Round 7
// 1572.179 us; speedup vs baseline: 1.8767x; 1.8767x over previous
//
#include <hip/hip_runtime.h>
#include <hip/hip_bf16.h>
#include <math.h>

#define T_STEPS 512
#define BATCH   1024

typedef __attribute__((ext_vector_type(8))) short short8;
typedef __attribute__((ext_vector_type(4))) float f32x4;

#define MFMA16(A, B, C) __builtin_amdgcn_mfma_f32_16x16x32_bf16((A), (B), (C), 0, 0, 0)

__device__ __forceinline__ float fast_sigm(float z) {
    return __fdividef(1.0f, 1.0f + __expf(-z));
}
__device__ __forceinline__ float fast_tanh(float z) {
    return fmaf(2.0f, __fdividef(1.0f, 1.0f + __expf(-2.0f * z)), -1.0f);
}
__device__ __forceinline__ unsigned short f2bf(float f) {
    unsigned int u = __float_as_uint(f);
    u += 0x7fffu + ((u >> 16) & 1u);
    return (unsigned short)(u >> 16);
}
// linear k-slot gather: element e <- p[e]  (A/B pair must both be LIN)
__device__ __forceinline__ short8 ldfrag_lin(const float* __restrict__ p) {
    short8 r;
#pragma unroll
    for (int e = 0; e < 8; ++e) r[e] = (short)f2bf(p[e]);
    return r;
}
// sigma2 gather: k-slot (lg,e) <-> col (e>>2)*16 + lg*4 + (e&3)  (pair with
// lane-natural in-register B-frags; verified by round-6 pass)
__device__ __forceinline__ short8 ldfrag_s2(const float* __restrict__ p, int lg) {
    short8 r;
#pragma unroll
    for (int e = 0; e < 8; ++e) r[e] = (short)f2bf(p[(e >> 2) * 16 + lg * 4 + (e & 3)]);
    return r;
}

// ===========================================================================
// K1: layer-1 REVERSE. 64 blocks x 512 thr = TWO independent chains (8
// batches each) x 4 waves -> 2 independent waves/SIMD (latency pooling).
// Inner loop = round-5-K1 (LIN frags, 1 barrier/step). Archives hr bf16 to
// ws as [t][batch][unit].
// ===========================================================================
__global__ __launch_bounds__(512, 1) void l1rev_kernel(
    const float* __restrict__ x,
    const float* __restrict__ whh1r, const float* __restrict__ wih1r,
    const float* __restrict__ b1r,
    unsigned short* __restrict__ arch)      // [T][BATCH][64]
{
    __shared__ __align__(16) float xT[T_STEPS][20];
    __shared__ __align__(16) short hrT[2][2][16][72];   // [chain][par][batch][unit]

    const int blk = blockIdx.x, tid = threadIdx.x;
    const int wv = tid >> 6, l = tid & 63, lg = l >> 4, lr = l & 15;
    const int c = wv >> 2, wvl = wv & 3;

    for (int i = tid; i < T_STEPS * 16; i += 512) {
        const int b = i >> 9, t = i & 511;
        xT[t][b] = x[(size_t)(blk * 16 + b) * T_STEPS + t];
    }
    for (int i = tid; i < 2 * 16 * 72; i += 512)
        hrT[i / (16 * 72)][0][(i / 72) & 15][i % 72] = 0;

    short8 BW[8]; float wihv[4], bvv[4];
#pragma unroll
    for (int g = 0; g < 4; ++g) {
        const int row = g * 64 + wvl * 16 + lr;
        BW[2 * g]     = ldfrag_lin(whh1r + row * 64 + lg * 8);
        BW[2 * g + 1] = ldfrag_lin(whh1r + row * 64 + 32 + lg * 8);
        wihv[g] = wih1r[row]; bvv[g] = b1r[row];
    }
    float cst[4] = {0.f, 0.f, 0.f, 0.f};
    __syncthreads();

    for (int t = T_STEPS - 1; t >= 0; --t) {
        const int rp = (t + 1) & 1;
        const short8 a0 = *(const short8*)&hrT[c][rp][lr][lg * 8];
        const short8 a1 = *(const short8*)&hrT[c][rp][lr][32 + lg * 8];
        f32x4 z[4];
#pragma unroll
        for (int g = 0; g < 4; ++g) {
            f32x4 za = {0.f, 0.f, 0.f, 0.f}, zb = {0.f, 0.f, 0.f, 0.f};
            za = MFMA16(a0, BW[2 * g], za);
            zb = MFMA16(a1, BW[2 * g + 1], zb);
            z[g] = za + zb;
        }
        if (lg < 2) {   // chain-local batches lg*4+j in [0,8)
            const float4 x4v = *(const float4*)&xT[t][c * 8 + lg * 4];
            const float xa[4] = {x4v.x, x4v.y, x4v.z, x4v.w};
#pragma unroll
            for (int j = 0; j < 4; ++j) {
                const float vi = fast_sigm(z[0][j] + fmaf(xa[j], wihv[0], bvv[0]));
                const float vf = fast_sigm(z[1][j] + fmaf(xa[j], wihv[1], bvv[1]));
                const float vg = fast_tanh(z[2][j] + fmaf(xa[j], wihv[2], bvv[2]));
                const float vo = fast_sigm(z[3][j] + fmaf(xa[j], wihv[3], bvv[3]));
                cst[j] = fmaf(vf, cst[j], vi * vg);
                const float h = vo * fast_tanh(cst[j]);
                const unsigned short hb = f2bf(h);
                hrT[c][t & 1][lg * 4 + j][wvl * 16 + lr] = (short)hb;
                arch[((size_t)t * BATCH + blk * 16 + c * 8 + lg * 4 + j) * 64
                     + wvl * 16 + lr] = hb;
            }
        }
        __syncthreads();
    }
}

// ===========================================================================
// K2: L1-FORWARD (waves 0-3, round-5-K1 structure, hf via LDS frontier) +
// L2 forward (waves 4-11: ONE M-tile per wave, 5 MFMA/step, acts exchange,
// exactly one c-update per thread, h2 republished LIN) + epilogue (wave 4:
// L2-reverse single step @ T-1 with zero state + MLP head, all MFMA).
// 64 blocks x 768 thr = 3 waves/SIMD. Two barriers/step, parity-disjoint.
// ===========================================================================
__global__ __launch_bounds__(768, 1) void l2fwd_kernel(
    const float* __restrict__ x,
    const float* __restrict__ wih1f, const float* __restrict__ whh1f, const float* __restrict__ b1f,
    const float* __restrict__ wih2f, const float* __restrict__ whh2f, const float* __restrict__ b2f,
    const float* __restrict__ wih2r, const float* __restrict__ b2r,
    const float* __restrict__ w_fc1, const float* __restrict__ b_fc1,
    const float* __restrict__ w_out, const float* __restrict__ b_out,
    const unsigned short* __restrict__ arch,
    float* __restrict__ out)
{
    __shared__ __align__(16) float xT[T_STEPS][20];     // 40 KB
    __shared__ __align__(16) short hfT[2][16][72];      // hf frontier dbuf [batch][unit]
    __shared__ __align__(16) float acts[2][16][132];    // [batch][gate-row] f32
    __shared__ __align__(16) short h2X[2][16][40];      // h2 dbuf [batch][unit] bf16

    const int blk = blockIdx.x, tid = threadIdx.x;
    const int wv = tid >> 6, l = tid & 63, lg = l >> 4, lr = l & 15;

    for (int i = tid; i < T_STEPS * 16; i += 768) {
        const int b = i >> 9, t = i & 511;
        xT[t][b] = x[(size_t)(blk * 16 + b) * T_STEPS + t];
    }
    for (int i = tid; i < 16 * 72; i += 768) hfT[1][i / 72][i % 72] = 0;
    for (int i = tid; i < 16 * 40; i += 768) h2X[1][i / 40][i % 40] = 0;

    short8 BW[8]; float wihv[4], bvv[4];    // waves 0-3 (L1 fwd)
    short8 AF[5]; float b2v[4];             // waves 4-11 (L2), tile m = wv-4
    short8 r0n = {0,0,0,0,0,0,0,0}, r1n = {0,0,0,0,0,0,0,0};
    float cst[4] = {0.f, 0.f, 0.f, 0.f};
    float c2 = 0.f;
    const int m = wv - 4;
    const int tid2 = tid - 256, uu = tid2 & 31, bb = tid2 >> 5;   // valid wv>=4

    if (wv < 4) {
#pragma unroll
        for (int g = 0; g < 4; ++g) {
            const int row = g * 64 + wv * 16 + lr;
            BW[2 * g]     = ldfrag_lin(whh1f + row * 64 + lg * 8);
            BW[2 * g + 1] = ldfrag_lin(whh1f + row * 64 + 32 + lg * 8);
            wihv[g] = wih1f[row]; bvv[g] = b1f[row];
        }
    } else {
        const int row = m * 16 + lr;
        AF[0] = ldfrag_lin(wih2f + row * 128 + lg * 8);        // hf k 0-31
        AF[1] = ldfrag_lin(wih2f + row * 128 + 32 + lg * 8);   // hf k 32-63
        AF[2] = ldfrag_lin(wih2f + row * 128 + 64 + lg * 8);   // hr k 0-31
        AF[3] = ldfrag_lin(wih2f + row * 128 + 96 + lg * 8);   // hr k 32-63
        AF[4] = ldfrag_lin(whh2f + row * 32 + lg * 8);         // h2 k 0-31
#pragma unroll
        for (int j = 0; j < 4; ++j) b2v[j] = b2f[m * 16 + lg * 4 + j];
        r0n = *(const short8*)(arch + ((size_t)blk * 16 + lr) * 64 + lg * 8);   // hr(0)
        r1n = *(const short8*)(arch + ((size_t)blk * 16 + lr) * 64 + 32 + lg * 8);
    }
    __syncthreads();

    f32x4 zf[4]; f32x4 zl;
    for (int i = 0; i <= T_STEPS; ++i) {
        // ---------------- phase 1: MFMA z + activations ----------------
        if (wv < 4) {
            if (i < T_STEPS) {
                const short8 a0 = *(const short8*)&hfT[(i + 1) & 1][lr][lg * 8];
                const short8 a1 = *(const short8*)&hfT[(i + 1) & 1][lr][32 + lg * 8];
#pragma unroll
                for (int g = 0; g < 4; ++g) {
                    f32x4 za = {0.f, 0.f, 0.f, 0.f}, zb = {0.f, 0.f, 0.f, 0.f};
                    za = MFMA16(a0, BW[2 * g], za);
                    zb = MFMA16(a1, BW[2 * g + 1], zb);
                    zf[g] = za + zb;
                }
            }
        } else if (i >= 1) {
            const int s = i - 1;
            const short8 f0 = *(const short8*)&hfT[s & 1][lr][lg * 8];
            const short8 f1 = *(const short8*)&hfT[s & 1][lr][32 + lg * 8];
            const short8 r0 = r0n, r1 = r1n;
            if (i < T_STEPS) {   // prefetch hr(i) for next iteration
                r0n = *(const short8*)(arch + ((size_t)i * BATCH + blk * 16 + lr) * 64 + lg * 8);
                r1n = *(const short8*)(arch + ((size_t)i * BATCH + blk * 16 + lr) * 64 + 32 + lg * 8);
            }
            const short8 h2f = *(const short8*)&h2X[i & 1][lr][lg * 8];   // h2(s-1)
            f32x4 za = {0.f, 0.f, 0.f, 0.f}, zb = {0.f, 0.f, 0.f, 0.f};
            za = MFMA16(AF[0], f0, za);
            za = MFMA16(AF[2], r0, za);
            zb = MFMA16(AF[1], f1, zb);
            zb = MFMA16(AF[3], r1, zb);
            zb = MFMA16(AF[4], h2f, zb);
            zl = za + zb;
            float av[4];
#pragma unroll
            for (int j = 0; j < 4; ++j) {
                const float zz = zl[j] + b2v[j];
                av[j] = ((m >> 1) == 2) ? fast_tanh(zz) : fast_sigm(zz);
            }
            *(float4*)&acts[s & 1][lr][m * 16 + lg * 4] =
                make_float4(av[0], av[1], av[2], av[3]);
        }
        __syncthreads();   // B1
        // ---------------- phase 2: c-updates + h publishes --------------
        if (wv < 4) {
            if (i < T_STEPS) {
                const float4 x4v = *(const float4*)&xT[i][lg * 4];
                const float xa[4] = {x4v.x, x4v.y, x4v.z, x4v.w};
#pragma unroll
                for (int j = 0; j < 4; ++j) {
                    const float vi = fast_sigm(zf[0][j] + fmaf(xa[j], wihv[0], bvv[0]));
                    const float vf = fast_sigm(zf[1][j] + fmaf(xa[j], wihv[1], bvv[1]));
                    const float vg = fast_tanh(zf[2][j] + fmaf(xa[j], wihv[2], bvv[2]));
                    const float vo = fast_sigm(zf[3][j] + fmaf(xa[j], wihv[3], bvv[3]));
                    cst[j] = fmaf(vf, cst[j], vi * vg);
                    const float h = vo * fast_tanh(cst[j]);
                    hfT[i & 1][lg * 4 + j][wv * 16 + lr] = (short)f2bf(h);
                }
            }
        } else if (i >= 1) {
            const int s = i - 1;
            const float gi = acts[s & 1][bb][uu];
            const float gf = acts[s & 1][bb][32 + uu];
            const float gg = acts[s & 1][bb][64 + uu];
            const float go = acts[s & 1][bb][96 + uu];
            c2 = fmaf(gf, c2, gi * gg);
            h2X[s & 1][bb][uu] = (short)f2bf(go * fast_tanh(c2));
        }
        __syncthreads();   // B2
    }

    // ===== epilogue (wave 4): L2-reverse single step @ T-1 + MLP head ======
    if (wv == 4) {
        short8 Bb = {0, 0, 0, 0, 0, 0, 0, 0};
        if (lg == 0) Bb[0] = (short)0x3F80;                   // B = [1, 0, ...]
        const short8 f0 = *(const short8*)&hfT[1][lr][lg * 8];         // hf(511)
        const short8 f1 = *(const short8*)&hfT[1][lr][32 + lg * 8];
        const short8 r0 = *(const short8*)(arch +
            ((size_t)(T_STEPS - 1) * BATCH + blk * 16 + lr) * 64 + lg * 8);    // hr(511)
        const short8 r1 = *(const short8*)(arch +
            ((size_t)(T_STEPS - 1) * BATCH + blk * 16 + lr) * 64 + 32 + lg * 8);
        f32x4 ze[8];
#pragma unroll
        for (int mm = 0; mm < 8; ++mm) {
            const int row = mm * 16 + lr;
            const short8 A0 = ldfrag_lin(wih2r + row * 128 + lg * 8);
            const short8 A1 = ldfrag_lin(wih2r + row * 128 + 32 + lg * 8);
            const short8 A2 = ldfrag_lin(wih2r + row * 128 + 64 + lg * 8);
            const short8 A3 = ldfrag_lin(wih2r + row * 128 + 96 + lg * 8);
            short8 bf = {0, 0, 0, 0, 0, 0, 0, 0};
            if (lg == 0) bf[0] = (short)f2bf(b2r[row]);
            f32x4 za = {0.f, 0.f, 0.f, 0.f}, zb = {0.f, 0.f, 0.f, 0.f};
            za = MFMA16(A0, f0, za);
            za = MFMA16(A2, r0, za);
            za = MFMA16(bf, Bb, za);
            zb = MFMA16(A1, f1, zb);
            zb = MFMA16(A3, r1, zb);
            ze[mm] = za + zb;
        }
        short8 BR = {0, 0, 0, 0, 0, 0, 0, 0};   // h2r(511), lane-natural sigma2
#pragma unroll
        for (int uh = 0; uh < 2; ++uh) {
#pragma unroll
            for (int j = 0; j < 4; ++j) {
                const float vi = fast_sigm(ze[uh][j]);          // c0=0: f-gate irrelevant
                const float vg = fast_tanh(ze[4 + uh][j]);
                const float vo = fast_sigm(ze[6 + uh][j]);
                BR[uh * 4 + j] = (short)f2bf(vo * fast_tanh(vi * vg));
            }
        }
        const short8 Bx = *(const short8*)&h2X[1][lr][lg * 8];  // h2f(511), LIN
        float part = 0.f;
#pragma unroll
        for (int mm = 0; mm < 4; ++mm) {
            const int row = mm * 16 + lr;
            const short8 A0 = ldfrag_lin(w_fc1 + row * 64 + lg * 8);   // cols 0-31 LIN
            const short8 A1 = ldfrag_s2(w_fc1 + row * 64 + 32, lg);    // cols 32-63 s2
            short8 bf = {0, 0, 0, 0, 0, 0, 0, 0};
            if (lg == 0) bf[0] = (short)f2bf(b_fc1[row]);
            f32x4 a = {0.f, 0.f, 0.f, 0.f};
            a = MFMA16(A0, Bx, a);
            a = MFMA16(A1, BR, a);
            a = MFMA16(bf, Bb, a);
#pragma unroll
            for (int j = 0; j < 4; ++j)
                part += fmaxf(a[j], 0.f) * w_out[mm * 16 + lg * 4 + j];
        }
        part += __shfl_xor(part, 16, 64);
        part += __shfl_xor(part, 32, 64);
        if (l < 16) out[blk * 16 + lr] = fast_sigm(part + b_out[0]);
    }
}

// ---------------------------------------------------------------------------
extern "C" void kernel_launch(void* const* d_in, const int* in_sizes, int n_in,
                              void* d_out, int out_size, void* d_ws, size_t ws_size,
                              hipStream_t stream) {
    const float* x     = (const float*)d_in[0];
    const float* wih1f = (const float*)d_in[1];
    const float* whh1f = (const float*)d_in[2];
    const float* b1f   = (const float*)d_in[3];
    const float* wih1r = (const float*)d_in[4];
    const float* whh1r = (const float*)d_in[5];
    const float* b1r   = (const float*)d_in[6];
    const float* wih2f = (const float*)d_in[7];
    const float* whh2f = (const float*)d_in[8];
    const float* b2f   = (const float*)d_in[9];
    const float* wih2r = (const float*)d_in[10];
    // d_in[11] = whh2r unused: layer-2 reverse runs exactly one step from zero state
    const float* b2r   = (const float*)d_in[12];
    const float* w_fc1 = (const float*)d_in[13];
    const float* b_fc1 = (const float*)d_in[14];
    const float* w_out = (const float*)d_in[15];
    const float* b_out = (const float*)d_in[16];
    float* out = (float*)d_out;

    // 64 MB hr archive [T][BATCH][64] bf16 — ws >= 64MB proven by rounds 4-6.
    unsigned short* arch = (unsigned short*)d_ws;

    l1rev_kernel<<<dim3(64), dim3(512), 0, stream>>>(x, whh1r, wih1r, b1r, arch);
    l2fwd_kernel<<<dim3(64), dim3(768), 0, stream>>>(
        x, wih1f, whh1f, b1f, wih2f, whh2f, b2f, wih2r, b2r,
        w_fc1, b_fc1, w_out, b_out, arch, out);
}

// Round 8
// 1025.413 us; speedup vs baseline: 2.8774x; 1.5332x over previous
//
#include <hip/hip_runtime.h>
#include <hip/hip_bf16.h>
#include <math.h>

#define T_STEPS 512
#define BATCH   1024

typedef __attribute__((ext_vector_type(8))) short short8;
typedef __attribute__((ext_vector_type(4))) float f32x4;

#define MFMA16(A, B, C) __builtin_amdgcn_mfma_f32_16x16x32_bf16((A), (B), (C), 0, 0, 0)

__device__ __forceinline__ float fast_sigm(float z) {
    return __fdividef(1.0f, 1.0f + __expf(-z));
}
__device__ __forceinline__ float fast_tanh(float z) {
    return fmaf(2.0f, __fdividef(1.0f, 1.0f + __expf(-2.0f * z)), -1.0f);
}
__device__ __forceinline__ unsigned short f2bf(float f) {
    unsigned int u = __float_as_uint(f);
    u += 0x7fffu + ((u >> 16) & 1u);
    return (unsigned short)(u >> 16);
}
// linear k-slot gather (A/B pair must both be LIN)
__device__ __forceinline__ short8 ldfrag_lin(const float* __restrict__ p) {
    short8 r;
#pragma unroll
    for (int e = 0; e < 8; ++e) r[e] = (short)f2bf(p[e]);
    return r;
}
// sigma2 gather: k-slot (lg,e) <-> col (e>>2)*16 + lg*4 + (e&3)
__device__ __forceinline__ short8 ldfrag_s2(const float* __restrict__ p, int lg) {
    short8 r;
#pragma unroll
    for (int e = 0; e < 8; ++e) r[e] = (short)f2bf(p[(e >> 2) * 16 + lg * 4 + (e & 3)]);
    return r;
}

// ===========================================================================
// K1-dual: layer-1 BOTH directions concurrently. 128 blocks x 256 thr.
// Even blocks: forward (t ascending) -> arch_f; odd: reverse -> arch_r.
// Inner loop = round-5 K1 (verified 1.02us/step). Archive layout per tile:
// [tile][t][batch16][unit64] bf16.
// ===========================================================================
__global__ __launch_bounds__(256, 1) void l1dual_kernel(
    const float* __restrict__ x,
    const float* __restrict__ whh1f, const float* __restrict__ wih1f, const float* __restrict__ b1f,
    const float* __restrict__ whh1r, const float* __restrict__ wih1r, const float* __restrict__ b1r,
    unsigned short* __restrict__ arch_f, unsigned short* __restrict__ arch_r)
{
    __shared__ __align__(16) float xT[T_STEPS][20];
    __shared__ __align__(16) short hT[2][16][72];

    const int blk = blockIdx.x;
    const int dir = blk & 1;            // 0 = fwd, 1 = rev
    const int tile = blk >> 1;
    const int tid = threadIdx.x;
    const int wv = tid >> 6, l = tid & 63, lg = l >> 4, lr = l & 15;

    const float* __restrict__ whh = dir ? whh1r : whh1f;
    const float* __restrict__ wih = dir ? wih1r : wih1f;
    const float* __restrict__ bbp = dir ? b1r : b1f;
    unsigned short* __restrict__ archb =
        (dir ? arch_r : arch_f) + (size_t)tile * T_STEPS * 16 * 64;

    for (int i = tid; i < T_STEPS * 16; i += 256) {
        const int b = i >> 9, t = i & 511;
        xT[t][b] = x[(size_t)(tile * 16 + b) * T_STEPS + t];
    }
    for (int i = tid; i < 2 * 16 * 72; i += 256) ((short*)hT)[i] = 0;

    short8 BW[8]; float wihv[4], bvv[4];
#pragma unroll
    for (int g = 0; g < 4; ++g) {
        const int row = g * 64 + wv * 16 + lr;
        BW[2 * g]     = ldfrag_lin(whh + row * 64 + lg * 8);
        BW[2 * g + 1] = ldfrag_lin(whh + row * 64 + 32 + lg * 8);
        wihv[g] = wih[row]; bvv[g] = bbp[row];
    }
    float cst[4] = {0.f, 0.f, 0.f, 0.f};
    __syncthreads();

    for (int i = 0; i < T_STEPS; ++i) {
        const int t = dir ? (T_STEPS - 1 - i) : i;
        const int rp = (t + 1) & 1;     // parity of previous step (both dirs)
        const short8 a0 = *(const short8*)&hT[rp][lr][lg * 8];
        const short8 a1 = *(const short8*)&hT[rp][lr][32 + lg * 8];
        f32x4 z[4];
#pragma unroll
        for (int g = 0; g < 4; ++g) {
            f32x4 za = {0.f, 0.f, 0.f, 0.f}, zb = {0.f, 0.f, 0.f, 0.f};
            za = MFMA16(a0, BW[2 * g], za);
            zb = MFMA16(a1, BW[2 * g + 1], zb);
            z[g] = za + zb;
        }
        const float4 x4v = *(const float4*)&xT[t][lg * 4];
        const float xa[4] = {x4v.x, x4v.y, x4v.z, x4v.w};
#pragma unroll
        for (int j = 0; j < 4; ++j) {
            const float vi = fast_sigm(z[0][j] + fmaf(xa[j], wihv[0], bvv[0]));
            const float vf = fast_sigm(z[1][j] + fmaf(xa[j], wihv[1], bvv[1]));
            const float vg = fast_tanh(z[2][j] + fmaf(xa[j], wihv[2], bvv[2]));
            const float vo = fast_sigm(z[3][j] + fmaf(xa[j], wihv[3], bvv[3]));
            cst[j] = fmaf(vf, cst[j], vi * vg);
            const float h = vo * fast_tanh(cst[j]);
            const unsigned short hb = f2bf(h);
            hT[t & 1][lg * 4 + j][wv * 16 + lr] = (short)hb;
            archb[((size_t)t * 16 + lg * 4 + j) * 64 + wv * 16 + lr] = hb;
        }
        __syncthreads();
    }
}

// ===========================================================================
// K3: layer-2 forward recurrence + rev step + head. 64 blocks x 512 thr
// (8 waves). GATE-INTERLEAVED rows: tile wv, tile-row r maps to original row
// orig(r) = (r&3)*32 + 4*wv + (r>>2)  =>  lane (lg,lr)'s C values z[j] are
// gates j=i,f,g,o of unit (4*wv+lg), batch lr -> c-update fully lane-local.
// zpre = Wih2f.[hf;hr] is software-pipelined one step ahead (4 MFMA off the
// critical path; archive frags prefetched 2 steps ahead). One barrier/step.
// ===========================================================================
__global__ __launch_bounds__(512, 1) void l2top_kernel(
    const float* __restrict__ wih2f, const float* __restrict__ whh2f, const float* __restrict__ b2f,
    const float* __restrict__ wih2r, const float* __restrict__ b2r,
    const float* __restrict__ w_fc1, const float* __restrict__ b_fc1,
    const float* __restrict__ w_out, const float* __restrict__ b_out,
    const unsigned short* __restrict__ arch_f, const unsigned short* __restrict__ arch_r,
    float* __restrict__ out)
{
    __shared__ __align__(16) short h2X[2][16][40];

    const int bt = blockIdx.x, tid = threadIdx.x;
    const int wv = tid >> 6, l = tid & 63, lg = l >> 4, lr = l & 15;
    const unsigned short* __restrict__ af = arch_f + (size_t)bt * T_STEPS * 16 * 64;
    const unsigned short* __restrict__ ar = arch_r + (size_t)bt * T_STEPS * 16 * 64;

    const int orow = (lr & 3) * 32 + 4 * wv + (lr >> 2);   // interleaved row map
    short8 AF[5];
    AF[0] = ldfrag_lin(wih2f + orow * 128 + lg * 8);        // hf k 0-31
    AF[1] = ldfrag_lin(wih2f + orow * 128 + 32 + lg * 8);   // hf k 32-63
    AF[2] = ldfrag_lin(wih2f + orow * 128 + 64 + lg * 8);   // hr k 0-31
    AF[3] = ldfrag_lin(wih2f + orow * 128 + 96 + lg * 8);   // hr k 32-63
    AF[4] = ldfrag_lin(whh2f + orow * 32 + lg * 8);         // h2 k 0-31
    float b2v[4];
#pragma unroll
    for (int j = 0; j < 4; ++j) b2v[j] = b2f[j * 32 + 4 * wv + lg];

    for (int i = tid; i < 2 * 16 * 40; i += 512) ((short*)h2X)[i] = 0;

    // prologue: zcur = zpre(0); prefetch frags for step 1
    short8 pf0 = *(const short8*)(af + (size_t)lr * 64 + lg * 8);
    short8 pf1 = *(const short8*)(af + (size_t)lr * 64 + 32 + lg * 8);
    short8 pr0 = *(const short8*)(ar + (size_t)lr * 64 + lg * 8);
    short8 pr1 = *(const short8*)(ar + (size_t)lr * 64 + 32 + lg * 8);
    f32x4 zcur = {0.f, 0.f, 0.f, 0.f};
    zcur = MFMA16(AF[0], pf0, zcur);
    zcur = MFMA16(AF[1], pf1, zcur);
    zcur = MFMA16(AF[2], pr0, zcur);
    zcur = MFMA16(AF[3], pr1, zcur);
    pf0 = *(const short8*)(af + (size_t)(1 * 16 + lr) * 64 + lg * 8);
    pf1 = *(const short8*)(af + (size_t)(1 * 16 + lr) * 64 + 32 + lg * 8);
    pr0 = *(const short8*)(ar + (size_t)(1 * 16 + lr) * 64 + lg * 8);
    pr1 = *(const short8*)(ar + (size_t)(1 * 16 + lr) * 64 + 32 + lg * 8);

    float c2 = 0.f;
    __syncthreads();

    for (int s = 0; s < T_STEPS; ++s) {
        // ---- critical path: Whh2.h2(s-1) + zcur -> gates -> c2 -> h2(s)
        const short8 bh = *(const short8*)&h2X[(s + 1) & 1][lr][lg * 8];
        const f32x4 z = MFMA16(AF[4], bh, zcur);
        // ---- off-path: zpre(s+1) from prefetched frags; prefetch (s+2)
        f32x4 znxt = {0.f, 0.f, 0.f, 0.f};
        znxt = MFMA16(AF[0], pf0, znxt);
        znxt = MFMA16(AF[1], pf1, znxt);
        znxt = MFMA16(AF[2], pr0, znxt);
        znxt = MFMA16(AF[3], pr1, znxt);
        if (s + 2 < T_STEPS) {
            pf0 = *(const short8*)(af + (size_t)((s + 2) * 16 + lr) * 64 + lg * 8);
            pf1 = *(const short8*)(af + (size_t)((s + 2) * 16 + lr) * 64 + 32 + lg * 8);
            pr0 = *(const short8*)(ar + (size_t)((s + 2) * 16 + lr) * 64 + lg * 8);
            pr1 = *(const short8*)(ar + (size_t)((s + 2) * 16 + lr) * 64 + 32 + lg * 8);
        }
        // ---- lane-local gates (j: 0=i 1=f 2=g 3=o of unit 4*wv+lg, batch lr)
        const float vi = fast_sigm(z[0] + b2v[0]);
        const float vf = fast_sigm(z[1] + b2v[1]);
        const float vg = fast_tanh(z[2] + b2v[2]);
        const float vo = fast_sigm(z[3] + b2v[3]);
        c2 = fmaf(vf, c2, vi * vg);
        h2X[s & 1][lr][4 * wv + lg] = (short)f2bf(vo * fast_tanh(c2));
        zcur = znxt;
        __syncthreads();
    }

    // ===== epilogue (wave 0): L2-reverse single step @ T-1 + MLP head ======
    if (wv == 0) {
        short8 Bb = {0, 0, 0, 0, 0, 0, 0, 0};
        if (lg == 0) Bb[0] = (short)0x3F80;                   // B = [1, 0, ...]
        const short8 f0 = *(const short8*)(af + (size_t)((T_STEPS - 1) * 16 + lr) * 64 + lg * 8);
        const short8 f1 = *(const short8*)(af + (size_t)((T_STEPS - 1) * 16 + lr) * 64 + 32 + lg * 8);
        const short8 r0 = *(const short8*)(ar + (size_t)((T_STEPS - 1) * 16 + lr) * 64 + lg * 8);
        const short8 r1 = *(const short8*)(ar + (size_t)((T_STEPS - 1) * 16 + lr) * 64 + 32 + lg * 8);
        f32x4 ze[8];
#pragma unroll
        for (int mm = 0; mm < 8; ++mm) {
            const int row = mm * 16 + lr;                     // gate-major LIN rows
            const short8 A0 = ldfrag_lin(wih2r + row * 128 + lg * 8);
            const short8 A1 = ldfrag_lin(wih2r + row * 128 + 32 + lg * 8);
            const short8 A2 = ldfrag_lin(wih2r + row * 128 + 64 + lg * 8);
            const short8 A3 = ldfrag_lin(wih2r + row * 128 + 96 + lg * 8);
            short8 bf = {0, 0, 0, 0, 0, 0, 0, 0};
            if (lg == 0) bf[0] = (short)f2bf(b2r[row]);
            f32x4 za = {0.f, 0.f, 0.f, 0.f}, zb = {0.f, 0.f, 0.f, 0.f};
            za = MFMA16(A0, f0, za);
            za = MFMA16(A2, r0, za);
            za = MFMA16(bf, Bb, za);
            zb = MFMA16(A1, f1, zb);
            zb = MFMA16(A3, r1, zb);
            ze[mm] = za + zb;
        }
        short8 BR = {0, 0, 0, 0, 0, 0, 0, 0};   // h2r(511), lane-natural sigma2
#pragma unroll
        for (int uh = 0; uh < 2; ++uh) {
#pragma unroll
            for (int j = 0; j < 4; ++j) {
                const float vi = fast_sigm(ze[uh][j]);        // c0=0: f-gate irrelevant
                const float vg = fast_tanh(ze[4 + uh][j]);
                const float vo = fast_sigm(ze[6 + uh][j]);
                BR[uh * 4 + j] = (short)f2bf(vo * fast_tanh(vi * vg));
            }
        }
        const short8 Bx = *(const short8*)&h2X[1][lr][lg * 8];  // h2f(511), LIN
        float part = 0.f;
#pragma unroll
        for (int mm = 0; mm < 4; ++mm) {
            const int row = mm * 16 + lr;
            const short8 A0 = ldfrag_lin(w_fc1 + row * 64 + lg * 8);   // cols 0-31 LIN
            const short8 A1 = ldfrag_s2(w_fc1 + row * 64 + 32, lg);    // cols 32-63 s2
            short8 bf = {0, 0, 0, 0, 0, 0, 0, 0};
            if (lg == 0) bf[0] = (short)f2bf(b_fc1[row]);
            f32x4 a = {0.f, 0.f, 0.f, 0.f};
            a = MFMA16(A0, Bx, a);
            a = MFMA16(A1, BR, a);
            a = MFMA16(bf, Bb, a);
#pragma unroll
            for (int j = 0; j < 4; ++j)
                part += fmaxf(a[j], 0.f) * w_out[mm * 16 + lg * 4 + j];
        }
        part += __shfl_xor(part, 16, 64);
        part += __shfl_xor(part, 32, 64);
        if (l < 16) out[bt * 16 + lr] = fast_sigm(part + b_out[0]);
    }
}

// ===========================================================================
// FALLBACK (ws < 128MB): round-7 kernels verbatim (passing at 1572 us).
// ===========================================================================
__global__ __launch_bounds__(512, 1) void l1rev_kernel(
    const float* __restrict__ x,
    const float* __restrict__ whh1r, const float* __restrict__ wih1r,
    const float* __restrict__ b1r,
    unsigned short* __restrict__ arch)      // [T][BATCH][64]
{
    __shared__ __align__(16) float xT[T_STEPS][20];
    __shared__ __align__(16) short hrT[2][2][16][72];

    const int blk = blockIdx.x, tid = threadIdx.x;
    const int wv = tid >> 6, l = tid & 63, lg = l >> 4, lr = l & 15;
    const int c = wv >> 2, wvl = wv & 3;

    for (int i = tid; i < T_STEPS * 16; i += 512) {
        const int b = i >> 9, t = i & 511;
        xT[t][b] = x[(size_t)(blk * 16 + b) * T_STEPS + t];
    }
    for (int i = tid; i < 2 * 16 * 72; i += 512)
        hrT[i / (16 * 72)][0][(i / 72) & 15][i % 72] = 0;

    short8 BW[8]; float wihv[4], bvv[4];
#pragma unroll
    for (int g = 0; g < 4; ++g) {
        const int row = g * 64 + wvl * 16 + lr;
        BW[2 * g]     = ldfrag_lin(whh1r + row * 64 + lg * 8);
        BW[2 * g + 1] = ldfrag_lin(whh1r + row * 64 + 32 + lg * 8);
        wihv[g] = wih1r[row]; bvv[g] = b1r[row];
    }
    float cst[4] = {0.f, 0.f, 0.f, 0.f};
    __syncthreads();

    for (int t = T_STEPS - 1; t >= 0; --t) {
        const int rp = (t + 1) & 1;
        const short8 a0 = *(const short8*)&hrT[c][rp][lr][lg * 8];
        const short8 a1 = *(const short8*)&hrT[c][rp][lr][32 + lg * 8];
        f32x4 z[4];
#pragma unroll
        for (int g = 0; g < 4; ++g) {
            f32x4 za = {0.f, 0.f, 0.f, 0.f}, zb = {0.f, 0.f, 0.f, 0.f};
            za = MFMA16(a0, BW[2 * g], za);
            zb = MFMA16(a1, BW[2 * g + 1], zb);
            z[g] = za + zb;
        }
        if (lg < 2) {
            const float4 x4v = *(const float4*)&xT[t][c * 8 + lg * 4];
            const float xa[4] = {x4v.x, x4v.y, x4v.z, x4v.w};
#pragma unroll
            for (int j = 0; j < 4; ++j) {
                const float vi = fast_sigm(z[0][j] + fmaf(xa[j], wihv[0], bvv[0]));
                const float vf = fast_sigm(z[1][j] + fmaf(xa[j], wihv[1], bvv[1]));
                const float vg = fast_tanh(z[2][j] + fmaf(xa[j], wihv[2], bvv[2]));
                const float vo = fast_sigm(z[3][j] + fmaf(xa[j], wihv[3], bvv[3]));
                cst[j] = fmaf(vf, cst[j], vi * vg);
                const float h = vo * fast_tanh(cst[j]);
                const unsigned short hb = f2bf(h);
                hrT[c][t & 1][lg * 4 + j][wvl * 16 + lr] = (short)hb;
                arch[((size_t)t * BATCH + blk * 16 + c * 8 + lg * 4 + j) * 64
                     + wvl * 16 + lr] = hb;
            }
        }
        __syncthreads();
    }
}

__global__ __launch_bounds__(768, 1) void l2fwd_kernel(
    const float* __restrict__ x,
    const float* __restrict__ wih1f, const float* __restrict__ whh1f, const float* __restrict__ b1f,
    const float* __restrict__ wih2f, const float* __restrict__ whh2f, const float* __restrict__ b2f,
    const float* __restrict__ wih2r, const float* __restrict__ b2r,
    const float* __restrict__ w_fc1, const float* __restrict__ b_fc1,
    const float* __restrict__ w_out, const float* __restrict__ b_out,
    const unsigned short* __restrict__ arch,
    float* __restrict__ out)
{
    __shared__ __align__(16) float xT[T_STEPS][20];
    __shared__ __align__(16) short hfT[2][16][72];
    __shared__ __align__(16) float acts[2][16][132];
    __shared__ __align__(16) short h2X[2][16][40];

    const int blk = blockIdx.x, tid = threadIdx.x;
    const int wv = tid >> 6, l = tid & 63, lg = l >> 4, lr = l & 15;

    for (int i = tid; i < T_STEPS * 16; i += 768) {
        const int b = i >> 9, t = i & 511;
        xT[t][b] = x[(size_t)(blk * 16 + b) * T_STEPS + t];
    }
    for (int i = tid; i < 16 * 72; i += 768) hfT[1][i / 72][i % 72] = 0;
    for (int i = tid; i < 16 * 40; i += 768) h2X[1][i / 40][i % 40] = 0;

    short8 BW[8]; float wihv[4], bvv[4];
    short8 AF[5]; float b2v[4];
    short8 r0n = {0,0,0,0,0,0,0,0}, r1n = {0,0,0,0,0,0,0,0};
    float cst[4] = {0.f, 0.f, 0.f, 0.f};
    float c2 = 0.f;
    const int m = wv - 4;
    const int tid2 = tid - 256, uu = tid2 & 31, bb = tid2 >> 5;

    if (wv < 4) {
#pragma unroll
        for (int g = 0; g < 4; ++g) {
            const int row = g * 64 + wv * 16 + lr;
            BW[2 * g]     = ldfrag_lin(whh1f + row * 64 + lg * 8);
            BW[2 * g + 1] = ldfrag_lin(whh1f + row * 64 + 32 + lg * 8);
            wihv[g] = wih1f[row]; bvv[g] = b1f[row];
        }
    } else {
        const int row = m * 16 + lr;
        AF[0] = ldfrag_lin(wih2f + row * 128 + lg * 8);
        AF[1] = ldfrag_lin(wih2f + row * 128 + 32 + lg * 8);
        AF[2] = ldfrag_lin(wih2f + row * 128 + 64 + lg * 8);
        AF[3] = ldfrag_lin(wih2f + row * 128 + 96 + lg * 8);
        AF[4] = ldfrag_lin(whh2f + row * 32 + lg * 8);
#pragma unroll
        for (int j = 0; j < 4; ++j) b2v[j] = b2f[m * 16 + lg * 4 + j];
        r0n = *(const short8*)(arch + ((size_t)blk * 16 + lr) * 64 + lg * 8);
        r1n = *(const short8*)(arch + ((size_t)blk * 16 + lr) * 64 + 32 + lg * 8);
    }
    __syncthreads();

    f32x4 zf[4]; f32x4 zl;
    for (int i = 0; i <= T_STEPS; ++i) {
        if (wv < 4) {
            if (i < T_STEPS) {
                const short8 a0 = *(const short8*)&hfT[(i + 1) & 1][lr][lg * 8];
                const short8 a1 = *(const short8*)&hfT[(i + 1) & 1][lr][32 + lg * 8];
#pragma unroll
                for (int g = 0; g < 4; ++g) {
                    f32x4 za = {0.f, 0.f, 0.f, 0.f}, zb = {0.f, 0.f, 0.f, 0.f};
                    za = MFMA16(a0, BW[2 * g], za);
                    zb = MFMA16(a1, BW[2 * g + 1], zb);
                    zf[g] = za + zb;
                }
            }
        } else if (i >= 1) {
            const int s = i - 1;
            const short8 f0 = *(const short8*)&hfT[s & 1][lr][lg * 8];
            const short8 f1 = *(const short8*)&hfT[s & 1][lr][32 + lg * 8];
            const short8 r0 = r0n, r1 = r1n;
            if (i < T_STEPS) {
                r0n = *(const short8*)(arch + ((size_t)i * BATCH + blk * 16 + lr) * 64 + lg * 8);
                r1n = *(const short8*)(arch + ((size_t)i * BATCH + blk * 16 + lr) * 64 + 32 + lg * 8);
            }
            const short8 h2f = *(const short8*)&h2X[i & 1][lr][lg * 8];
            f32x4 za = {0.f, 0.f, 0.f, 0.f}, zb = {0.f, 0.f, 0.f, 0.f};
            za = MFMA16(AF[0], f0, za);
            za = MFMA16(AF[2], r0, za);
            zb = MFMA16(AF[1], f1, zb);
            zb = MFMA16(AF[3], r1, zb);
            zb = MFMA16(AF[4], h2f, zb);
            zl = za + zb;
            float av[4];
#pragma unroll
            for (int j = 0; j < 4; ++j) {
                const float zz = zl[j] + b2v[j];
                av[j] = ((m >> 1) == 2) ? fast_tanh(zz) : fast_sigm(zz);
            }
            *(float4*)&acts[s & 1][lr][m * 16 + lg * 4] =
                make_float4(av[0], av[1], av[2], av[3]);
        }
        __syncthreads();
        if (wv < 4) {
            if (i < T_STEPS) {
                const float4 x4v = *(const float4*)&xT[i][lg * 4];
                const float xa[4] = {x4v.x, x4v.y, x4v.z, x4v.w};
#pragma unroll
                for (int j = 0; j < 4; ++j) {
                    const float vi = fast_sigm(zf[0][j] + fmaf(xa[j], wihv[0], bvv[0]));
                    const float vf = fast_sigm(zf[1][j] + fmaf(xa[j], wihv[1], bvv[1]));
                    const float vg = fast_tanh(zf[2][j] + fmaf(xa[j], wihv[2], bvv[2]));
                    const float vo = fast_sigm(zf[3][j] + fmaf(xa[j], wihv[3], bvv[3]));
                    cst[j] = fmaf(vf, cst[j], vi * vg);
                    const float h = vo * fast_tanh(cst[j]);
                    hfT[i & 1][lg * 4 + j][wv * 16 + lr] = (short)f2bf(h);
                }
            }
        } else if (i >= 1) {
            const int s = i - 1;
            const float gi = acts[s & 1][bb][uu];
            const float gf = acts[s & 1][bb][32 + uu];
            const float gg = acts[s & 1][bb][64 + uu];
            const float go = acts[s & 1][bb][96 + uu];
            c2 = fmaf(gf, c2, gi * gg);
            h2X[s & 1][bb][uu] = (short)f2bf(go * fast_tanh(c2));
        }
        __syncthreads();
    }

    if (wv == 4) {
        short8 Bb = {0, 0, 0, 0, 0, 0, 0, 0};
        if (lg == 0) Bb[0] = (short)0x3F80;
        const short8 f0 = *(const short8*)&hfT[1][lr][lg * 8];
        const short8 f1 = *(const short8*)&hfT[1][lr][32 + lg * 8];
        const short8 r0 = *(const short8*)(arch +
            ((size_t)(T_STEPS - 1) * BATCH + blk * 16 + lr) * 64 + lg * 8);
        const short8 r1 = *(const short8*)(arch +
            ((size_t)(T_STEPS - 1) * BATCH + blk * 16 + lr) * 64 + 32 + lg * 8);
        f32x4 ze[8];
#pragma unroll
        for (int mm = 0; mm < 8; ++mm) {
            const int row = mm * 16 + lr;
            const short8 A0 = ldfrag_lin(wih2r + row * 128 + lg * 8);
            const short8 A1 = ldfrag_lin(wih2r + row * 128 + 32 + lg * 8);
            const short8 A2 = ldfrag_lin(wih2r + row * 128 + 64 + lg * 8);
            const short8 A3 = ldfrag_lin(wih2r + row * 128 + 96 + lg * 8);
            short8 bf = {0, 0, 0, 0, 0, 0, 0, 0};
            if (lg == 0) bf[0] = (short)f2bf(b2r[row]);
            f32x4 za = {0.f, 0.f, 0.f, 0.f}, zb = {0.f, 0.f, 0.f, 0.f};
            za = MFMA16(A0, f0, za);
            za = MFMA16(A2, r0, za);
            za = MFMA16(bf, Bb, za);
            zb = MFMA16(A1, f1, zb);
            zb = MFMA16(A3, r1, zb);
            ze[mm] = za + zb;
        }
        short8 BR = {0, 0, 0, 0, 0, 0, 0, 0};
#pragma unroll
        for (int uh = 0; uh < 2; ++uh) {
#pragma unroll
            for (int j = 0; j < 4; ++j) {
                const float vi = fast_sigm(ze[uh][j]);
                const float vg = fast_tanh(ze[4 + uh][j]);
                const float vo = fast_sigm(ze[6 + uh][j]);
                BR[uh * 4 + j] = (short)f2bf(vo * fast_tanh(vi * vg));
            }
        }
        const short8 Bx = *(const short8*)&h2X[1][lr][lg * 8];
        float part = 0.f;
#pragma unroll
        for (int mm = 0; mm < 4; ++mm) {
            const int row = mm * 16 + lr;
            const short8 A0 = ldfrag_lin(w_fc1 + row * 64 + lg * 8);
            const short8 A1 = ldfrag_s2(w_fc1 + row * 64 + 32, lg);
            short8 bf = {0, 0, 0, 0, 0, 0, 0, 0};
            if (lg == 0) bf[0] = (short)f2bf(b_fc1[row]);
            f32x4 a = {0.f, 0.f, 0.f, 0.f};
            a = MFMA16(A0, Bx, a);
            a = MFMA16(A1, BR, a);
            a = MFMA16(bf, Bb, a);
#pragma unroll
            for (int j = 0; j < 4; ++j)
                part += fmaxf(a[j], 0.f) * w_out[mm * 16 + lg * 4 + j];
        }
        part += __shfl_xor(part, 16, 64);
        part += __shfl_xor(part, 32, 64);
        if (l < 16) out[blk * 16 + lr] = fast_sigm(part + b_out[0]);
    }
}

// ---------------------------------------------------------------------------
extern "C" void kernel_launch(void* const* d_in, const int* in_sizes, int n_in,
                              void* d_out, int out_size, void* d_ws, size_t ws_size,
                              hipStream_t stream) {
    const float* x     = (const float*)d_in[0];
    const float* wih1f = (const float*)d_in[1];
    const float* whh1f = (const float*)d_in[2];
    const float* b1f   = (const float*)d_in[3];
    const float* wih1r = (const float*)d_in[4];
    const float* whh1r = (const float*)d_in[5];
    const float* b1r   = (const float*)d_in[6];
    const float* wih2f = (const float*)d_in[7];
    const float* whh2f = (const float*)d_in[8];
    const float* b2f   = (const float*)d_in[9];
    const float* wih2r = (const float*)d_in[10];
    // d_in[11] = whh2r unused: layer-2 reverse runs exactly one step from zero state
    const float* b2r   = (const float*)d_in[12];
    const float* w_fc1 = (const float*)d_in[13];
    const float* b_fc1 = (const float*)d_in[14];
    const float* w_out = (const float*)d_in[15];
    const float* b_out = (const float*)d_in[16];
    float* out = (float*)d_out;

    const size_t dir_bytes = (size_t)64 * T_STEPS * 16 * 64 * sizeof(unsigned short); // 64 MB
    if (ws_size >= 2 * dir_bytes) {
        unsigned short* arch_f = (unsigned short*)d_ws;
        unsigned short* arch_r = arch_f + (size_t)64 * T_STEPS * 16 * 64;
        l1dual_kernel<<<dim3(128), dim3(256), 0, stream>>>(
            x, whh1f, wih1f, b1f, whh1r, wih1r, b1r, arch_f, arch_r);
        l2top_kernel<<<dim3(64), dim3(512), 0, stream>>>(
            wih2f, whh2f, b2f, wih2r, b2r,
            w_fc1, b_fc1, w_out, b_out, arch_f, arch_r, out);
    } else {
        unsigned short* arch = (unsigned short*)d_ws;   // 64 MB [T][BATCH][64]
        l1rev_kernel<<<dim3(64), dim3(512), 0, stream>>>(x, whh1r, wih1r, b1r, arch);
        l2fwd_kernel<<<dim3(64), dim3(768), 0, stream>>>(
            x, wih1f, whh1f, b1f, wih2f, whh2f, b2f, wih2r, b2r,
            w_fc1, b_fc1, w_out, b_out, arch, out);
    }
}